// Round 1
// 605.837 us; speedup vs baseline: 1.0271x; 1.0271x over previous
//
#include <hip/hip_runtime.h>

typedef unsigned short ushort_t;
typedef short s8v __attribute__((ext_vector_type(8)));
typedef unsigned short ushort8 __attribute__((ext_vector_type(8)));
typedef float floatx4 __attribute__((ext_vector_type(4)));

#define MFMA16(a, b, c) __builtin_amdgcn_mfma_f32_16x16x32_bf16((a), (b), (c), 0, 0, 0)

static constexpr int B_SZ = 8;
static constexpr int L = 8192;
static constexpr int H = 1024;
static constexpr int P = 64;
static constexpr int M_TOT = B_SZ * L;        // 65536 rows
static constexpr int S_CH = 64;               // chunk length for scan
static constexpr int NC = L / S_CH;           // 128 chunks per batch

// round-to-nearest-even fp32 -> bf16 bits
__device__ inline ushort_t f2bf(float f) {
    union { float f; unsigned u; } v; v.f = f;
    unsigned r = v.u + 0x7fffu + ((v.u >> 16) & 1u);
    return (ushort_t)(r >> 16);
}

// ---------------------------------------------------------------- params ----
// params[0..63]=dA_r [64..127]=dA_i [128..191]=s_r [192..255]=s_i
// dApow INTERLEAVED: dApow[k*128 + 2p] = Re(dA^k), [k*128 + 2p+1] = Im(dA^k),
// k = 0..S_CH
__global__ void params_kernel(const float* __restrict__ A_real,
                              const float* __restrict__ A_imag,
                              const float* __restrict__ inv_dt,
                              float* __restrict__ params,
                              float* __restrict__ dApow) {
    int p = threadIdx.x;  // 64 threads
    float x = inv_dt[p];
    float dt = (x > 20.f) ? x : log1pf(expf(x));
    float ar = A_real[p], ai = A_imag[p];
    float dr = 1.f - 0.5f * dt * ar;
    float di = -0.5f * dt * ai;
    float inv = 1.f / fmaf(dr, dr, di * di);
    float nr = 1.f + 0.5f * dt * ar, ni = 0.5f * dt * ai;
    float dAr = (nr * dr + ni * di) * inv;
    float dAi = (ni * dr - nr * di) * inv;
    params[p]       = dAr;
    params[64 + p]  = dAi;
    params[128 + p] = dt * dr * inv;    // Re(dt/den)
    params[192 + p] = -dt * di * inv;   // Im(dt/den)
    float pr = 1.f, pi = 0.f;
    dApow[2 * p] = 1.f; dApow[2 * p + 1] = 0.f;
    for (int k = 1; k <= S_CH; k++) {
        float npr = pr * dAr - pi * dAi;
        float npi = pr * dAi + pi * dAr;
        pr = npr; pi = npi;
        dApow[k * 128 + 2 * p]     = pr;
        dApow[k * 128 + 2 * p + 1] = pi;
    }
}

// -------------------------------------------------- build bf16 weights ----
// INTERLEAVED rows: W1T[2p][k]   = Re(s_p * B[p][k])
//                   W1T[2p+1][k] = Im(s_p * B[p][k])
// CeffT[h][2p] = 2*C_r[h][p];  CeffT[h][2p+1] = -2*C_i[h][p]
__global__ void build_w(const float* __restrict__ Br, const float* __restrict__ Bi,
                        const float* __restrict__ Cr, const float* __restrict__ Ci,
                        const float* __restrict__ params,
                        ushort_t* __restrict__ W1T, ushort_t* __restrict__ CeffT) {
    int t = blockIdx.x * 256 + threadIdx.x;
    if (t < 128 * 1024) {
        int n = t >> 10, k = t & 1023;
        int p = n >> 1;
        float sr = params[128 + p], si = params[192 + p];
        float br = Br[p * 1024 + k], bi = Bi[p * 1024 + k];
        float v = (n & 1) ? (sr * bi + si * br) : (sr * br - si * bi);
        W1T[t] = f2bf(v);
    } else {
        int t2 = t - 128 * 1024;
        int h = t2 >> 7, k = t2 & 127;
        int p = k >> 1;
        float v = (k & 1) ? -2.f * Ci[h * 64 + p] : 2.f * Cr[h * 64 + p];
        CeffT[t2] = f2bf(v);
    }
}

// ------------------------------------------------------------- GEMM 1 ----
// Bu[M_TOT][128] = u[M_TOT][1024] @ W, W[k][n] = W1T[n][k]. 128-row tile/block.
// Output cols interleaved: col 2p = Re(Bu_p), col 2p+1 = Im(Bu_p).
__global__ __launch_bounds__(256) void gemm1(const float* __restrict__ u,
                                             const ushort_t* __restrict__ W1T,
                                             float* __restrict__ Bu) {
    __shared__ ushort_t As[128][40];  // [row][k], pad 32->40 (stride 80B)
    __shared__ ushort_t Bs[128][40];  // [n][k]
    int tid = threadIdx.x;
    int wave = tid >> 6, lane = tid & 63;
    int q = lane >> 4, mn = lane & 15;
    size_t row0 = (size_t)blockIdx.x * 128;
    int r = tid >> 1, half = tid & 1;

    floatx4 acc[2][8] = {};

    for (int kk = 0; kk < 1024; kk += 32) {
        __syncthreads();
        {
            const float4* up = (const float4*)(u + (row0 + r) * 1024 + kk + half * 16);
            float4 f0 = up[0], f1 = up[1], f2 = up[2], f3 = up[3];
            ushort8 t0, t1;
            t0[0] = f2bf(f0.x); t0[1] = f2bf(f0.y); t0[2] = f2bf(f0.z); t0[3] = f2bf(f0.w);
            t0[4] = f2bf(f1.x); t0[5] = f2bf(f1.y); t0[6] = f2bf(f1.z); t0[7] = f2bf(f1.w);
            t1[0] = f2bf(f2.x); t1[1] = f2bf(f2.y); t1[2] = f2bf(f2.z); t1[3] = f2bf(f2.w);
            t1[4] = f2bf(f3.x); t1[5] = f2bf(f3.y); t1[6] = f2bf(f3.z); t1[7] = f2bf(f3.w);
            ushort8* dst = (ushort8*)&As[r][half * 16];
            dst[0] = t0; dst[1] = t1;
            const ushort8* wp = (const ushort8*)(W1T + r * 1024 + kk + half * 16);
            ushort8* db = (ushort8*)&Bs[r][half * 16];
            db[0] = wp[0]; db[1] = wp[1];
        }
        __syncthreads();
        s8v a0 = *(const s8v*)&As[wave * 32 + mn][q * 8];
        s8v a1 = *(const s8v*)&As[wave * 32 + 16 + mn][q * 8];
        #pragma unroll
        for (int j = 0; j < 8; j++) {
            s8v bf = *(const s8v*)&Bs[j * 16 + mn][q * 8];
            acc[0][j] = MFMA16(a0, bf, acc[0][j]);
            acc[1][j] = MFMA16(a1, bf, acc[1][j]);
        }
    }
    #pragma unroll
    for (int i = 0; i < 2; i++)
        #pragma unroll
        for (int j = 0; j < 8; j++)
            #pragma unroll
            for (int reg = 0; reg < 4; reg++) {
                size_t row = row0 + wave * 32 + i * 16 + q * 4 + reg;
                Bu[row * 128 + j * 16 + mn] = acc[i][j][reg];
            }
}

// --------------------------------------------------------- local scan ----
// In-place: Bu becomes h_loc (local prefix with ZERO initial state per chunk;
// h0 is folded into carry[0] instead). One wave per chunk, 4 chunks/block.
// Lane p handles complex p via a single float2 (interleaved layout).
__global__ __launch_bounds__(256) void scan_local(float* __restrict__ Bu,
                                                  const float* __restrict__ params,
                                                  float* __restrict__ endbuf) {
    int tid = threadIdx.x;
    int p = tid & 63;
    int chunk = blockIdx.x * 4 + (tid >> 6);   // 1024 chunks total
    int b = chunk >> 7, c = chunk & (NC - 1);
    float dAr = params[p], dAi = params[64 + p];
    float* base = Bu + ((size_t)b * L + (size_t)c * S_CH) * 128 + 2 * p;
    float hr = 0.f, hi = 0.f;
    float2 cur = *(const float2*)base;
    float2 nxt;
    #pragma unroll 4
    for (int l = 0; l < S_CH; l++) {
        if (l < S_CH - 1) nxt = *(const float2*)(base + (size_t)(l + 1) * 128);
        float nhr = fmaf(dAr, hr, fmaf(-dAi, hi, cur.x));
        float nhi = fmaf(dAr, hi, fmaf(dAi, hr, cur.y));
        hr = nhr; hi = nhi;
        *(float2*)(base + (size_t)l * 128) = make_float2(hr, hi);
        cur = nxt;
    }
    float* e = endbuf + (size_t)chunk * 128 + 2 * p;
    e[0] = hr; e[1] = hi;
}

// --------------------------------------------------------- carry scan ----
// carry[c] = state entering chunk c; carry[0] = h0 (folds initial state).
__global__ void scan_carry(const float* __restrict__ endbuf,
                           const float* __restrict__ dApow,
                           const float* __restrict__ h0r,
                           const float* __restrict__ h0i,
                           float* __restrict__ carry) {
    int t = blockIdx.x * 64 + threadIdx.x;  // 512 = 8*64
    int b = t >> 6, p = t & 63;
    float aSr = dApow[S_CH * 128 + 2 * p], aSi = dApow[S_CH * 128 + 2 * p + 1];
    float cr = h0r[b * 64 + p], ci = h0i[b * 64 + p];
    for (int c = 0; c < NC; c++) {
        float* dst = carry + ((size_t)b * NC + c) * 128 + 2 * p;
        dst[0] = cr; dst[1] = ci;
        const float* e = endbuf + ((size_t)b * NC + c) * 128 + 2 * p;
        float er = e[0], ei = e[1];
        float nr = fmaf(aSr, cr, fmaf(-aSi, ci, er));
        float ni = fmaf(aSr, ci, fmaf(aSi, cr, ei));
        cr = nr; ci = ni;
    }
}

// ------------------------------------------------------------- GEMM 2 ----
// Fused fixup + GEMM: A-staging reads h_loc (f32), applies carry correction
// hfix = h_loc + dA^((l mod S)+1) * carry[chunk], converts to bf16 into LDS.
// Also emits h_last (f32, corrected) for rows with l == L-1.
// y[row][h] = sum_k hfix[row][k] * CeffT[h][k] + D[h]*u[row][h]
__global__ __launch_bounds__(256) void gemm2(const float* __restrict__ hloc,
                                             const ushort_t* __restrict__ CeffT,
                                             const float* __restrict__ u,
                                             const float* __restrict__ D,
                                             const float* __restrict__ dApow,
                                             const float* __restrict__ carry,
                                             float* __restrict__ y,
                                             float* __restrict__ out_hlast) {
    __shared__ ushort_t As[128][136];  // [row][k] K=128, stride 272B
    __shared__ ushort_t Bs[128][136];  // [n][k]
    int tid = threadIdx.x;
    int wave = tid >> 6, lane = tid & 63;
    int q = lane >> 4, mn = lane & 15;
    size_t row0 = (size_t)blockIdx.x * 128;
    int r = tid >> 1, half = tid & 1;
    {
        size_t rrow = row0 + r;
        int b = (int)(rrow >> 13);
        int l = (int)(rrow & (L - 1));
        int c = l >> 6;                 // l / S_CH
        int kp = (l & (S_CH - 1)) + 1;
        const float4* hp = (const float4*)(hloc + rrow * 128 + half * 64);
        const float4* pw = (const float4*)(dApow + (size_t)kp * 128 + half * 64);
        const float4* cv = (const float4*)(carry + ((size_t)b * NC + c) * 128 + half * 64);
        ushort8* dst = (ushort8*)&As[r][half * 64];
        bool last = (l == L - 1);
        #pragma unroll
        for (int j = 0; j < 8; j++) {
            float4 hv0 = hp[2 * j], hv1 = hp[2 * j + 1];
            float4 p0 = pw[2 * j], p1 = pw[2 * j + 1];
            float4 c0 = cv[2 * j], c1 = cv[2 * j + 1];
            float r0 = hv0.x + p0.x * c0.x - p0.y * c0.y;
            float i0 = hv0.y + p0.x * c0.y + p0.y * c0.x;
            float r1 = hv0.z + p0.z * c0.z - p0.w * c0.w;
            float i1 = hv0.w + p0.z * c0.w + p0.w * c0.z;
            float r2 = hv1.x + p1.x * c1.x - p1.y * c1.y;
            float i2 = hv1.y + p1.x * c1.y + p1.y * c1.x;
            float r3 = hv1.z + p1.z * c1.z - p1.w * c1.w;
            float i3 = hv1.w + p1.z * c1.w + p1.w * c1.z;
            ushort8 o;
            o[0] = f2bf(r0); o[1] = f2bf(i0); o[2] = f2bf(r1); o[3] = f2bf(i1);
            o[4] = f2bf(r2); o[5] = f2bf(i2); o[6] = f2bf(r3); o[7] = f2bf(i3);
            dst[j] = o;
            if (last) {
                int pb = (half * 64 + j * 8) >> 1;
                out_hlast[b * 64 + pb]           = r0; out_hlast[512 + b * 64 + pb]     = i0;
                out_hlast[b * 64 + pb + 1]       = r1; out_hlast[512 + b * 64 + pb + 1] = i1;
                out_hlast[b * 64 + pb + 2]       = r2; out_hlast[512 + b * 64 + pb + 2] = i2;
                out_hlast[b * 64 + pb + 3]       = r3; out_hlast[512 + b * 64 + pb + 3] = i3;
            }
        }
    }
    for (int ct = 0; ct < 8; ct++) {
        __syncthreads();
        {
            const ushort8* src = (const ushort8*)(CeffT + (size_t)(ct * 128 + r) * 128 + half * 64);
            ushort8* dst = (ushort8*)&Bs[r][half * 64];
            #pragma unroll
            for (int i = 0; i < 8; i++) dst[i] = src[i];
        }
        __syncthreads();
        floatx4 acc[2][8] = {};
        #pragma unroll
        for (int kk = 0; kk < 128; kk += 32) {
            s8v a0 = *(const s8v*)&As[wave * 32 + mn][kk + q * 8];
            s8v a1 = *(const s8v*)&As[wave * 32 + 16 + mn][kk + q * 8];
            #pragma unroll
            for (int j = 0; j < 8; j++) {
                s8v bf = *(const s8v*)&Bs[j * 16 + mn][kk + q * 8];
                acc[0][j] = MFMA16(a0, bf, acc[0][j]);
                acc[1][j] = MFMA16(a1, bf, acc[1][j]);
            }
        }
        float dv[8];
        #pragma unroll
        for (int j = 0; j < 8; j++) dv[j] = D[ct * 128 + j * 16 + mn];
        #pragma unroll
        for (int i = 0; i < 2; i++)
            #pragma unroll
            for (int j = 0; j < 8; j++) {
                int col = ct * 128 + j * 16 + mn;
                #pragma unroll
                for (int reg = 0; reg < 4; reg++) {
                    size_t row = row0 + wave * 32 + i * 16 + q * 4 + reg;
                    y[row * 1024 + col] = acc[i][j][reg] + dv[j] * u[row * 1024 + col];
                }
            }
    }
}

// -------------------------------------------------------------- launch ----
extern "C" void kernel_launch(void* const* d_in, const int* in_sizes, int n_in,
                              void* d_out, int out_size, void* d_ws, size_t ws_size,
                              hipStream_t stream) {
    const float* u      = (const float*)d_in[0];
    const float* h_r    = (const float*)d_in[1];
    const float* h_i    = (const float*)d_in[2];
    const float* A_real = (const float*)d_in[3];
    const float* A_imag = (const float*)d_in[4];
    const float* B_real = (const float*)d_in[5];
    const float* B_imag = (const float*)d_in[6];
    const float* C_real = (const float*)d_in[7];
    const float* C_imag = (const float*)d_in[8];
    const float* D      = (const float*)d_in[9];
    const float* inv_dt = (const float*)d_in[10];
    float* out = (float*)d_out;

    // workspace layout (floats from base; all 16B aligned)
    float* wsf       = (float*)d_ws;
    float* P_params  = wsf;                    // 256 used, reserve 1024
    float* P_dApow   = wsf + 1024;             // 65*128 = 8320, reserve 8448
    float* P_carry   = wsf + 1024 + 8448;      // 8*NC*128 = 131072
    float* P_end     = P_carry + 131072;       // 131072
    ushort_t* P_W1T  = (ushort_t*)(P_end + 131072);     // 128*1024 bf16
    ushort_t* P_Ceff = P_W1T + 128 * 1024;              // 1024*128 bf16
    float* P_Bu      = (float*)(P_Ceff + 1024 * 128);   // 65536*128 f32 (33.5MB)

    params_kernel<<<1, 64, 0, stream>>>(A_real, A_imag, inv_dt, P_params, P_dApow);
    build_w<<<1024, 256, 0, stream>>>(B_real, B_imag, C_real, C_imag, P_params, P_W1T, P_Ceff);
    gemm1<<<M_TOT / 128, 256, 0, stream>>>(u, P_W1T, P_Bu);
    scan_local<<<B_SZ * NC / 4, 256, 0, stream>>>(P_Bu, P_params, P_end);
    scan_carry<<<8, 64, 0, stream>>>(P_end, P_dApow, h_r, h_i, P_carry);
    gemm2<<<M_TOT / 128, 256, 0, stream>>>(P_Bu, P_Ceff, u, D, P_dApow, P_carry,
                                           out, out + (size_t)M_TOT * H);
}

// Round 2
// 592.162 us; speedup vs baseline: 1.0508x; 1.0231x over previous
//
#include <hip/hip_runtime.h>

typedef unsigned short ushort_t;
typedef short s8v __attribute__((ext_vector_type(8)));
typedef unsigned short ushort8 __attribute__((ext_vector_type(8)));
typedef float floatx4 __attribute__((ext_vector_type(4)));

#define MFMA16(a, b, c) __builtin_amdgcn_mfma_f32_16x16x32_bf16((a), (b), (c), 0, 0, 0)

static constexpr int B_SZ = 8;
static constexpr int L = 8192;
static constexpr int H = 1024;
static constexpr int M_TOT = B_SZ * L;        // 65536 rows
static constexpr int S_CH = 128;              // chunk length == gemm1 row-tile
static constexpr int NC = L / S_CH;           // 64 chunks per batch

// round-to-nearest-even fp32 -> bf16 bits
__device__ inline ushort_t f2bf(float f) {
    union { float f; unsigned u; } v; v.f = f;
    unsigned r = v.u + 0x7fffu + ((v.u >> 16) & 1u);
    return (ushort_t)(r >> 16);
}

// ---------------------------------------------------------------- params ----
// params[0..63]=dA_r [64..127]=dA_i [128..191]=s_r [192..255]=s_i
// dApow INTERLEAVED: dApow[k*128 + 2p] = Re(dA^k), [k*128 + 2p+1] = Im(dA^k),
// k = 0..S_CH (S_CH = 128)
__global__ void params_kernel(const float* __restrict__ A_real,
                              const float* __restrict__ A_imag,
                              const float* __restrict__ inv_dt,
                              float* __restrict__ params,
                              float* __restrict__ dApow) {
    int p = threadIdx.x;  // 64 threads
    float x = inv_dt[p];
    float dt = (x > 20.f) ? x : log1pf(expf(x));
    float ar = A_real[p], ai = A_imag[p];
    float dr = 1.f - 0.5f * dt * ar;
    float di = -0.5f * dt * ai;
    float inv = 1.f / fmaf(dr, dr, di * di);
    float nr = 1.f + 0.5f * dt * ar, ni = 0.5f * dt * ai;
    float dAr = (nr * dr + ni * di) * inv;
    float dAi = (ni * dr - nr * di) * inv;
    params[p]       = dAr;
    params[64 + p]  = dAi;
    params[128 + p] = dt * dr * inv;    // Re(dt/den)
    params[192 + p] = -dt * di * inv;   // Im(dt/den)
    float pr = 1.f, pi = 0.f;
    dApow[2 * p] = 1.f; dApow[2 * p + 1] = 0.f;
    for (int k = 1; k <= S_CH; k++) {
        float npr = pr * dAr - pi * dAi;
        float npi = pr * dAi + pi * dAr;
        pr = npr; pi = npi;
        dApow[k * 128 + 2 * p]     = pr;
        dApow[k * 128 + 2 * p + 1] = pi;
    }
}

// -------------------------------------------------- build bf16 weights ----
// INTERLEAVED rows: W1T[2p][k]   = Re(s_p * B[p][k])
//                   W1T[2p+1][k] = Im(s_p * B[p][k])
// CeffT[h][2p] = 2*C_r[h][p];  CeffT[h][2p+1] = -2*C_i[h][p]
__global__ void build_w(const float* __restrict__ Br, const float* __restrict__ Bi,
                        const float* __restrict__ Cr, const float* __restrict__ Ci,
                        const float* __restrict__ params,
                        ushort_t* __restrict__ W1T, ushort_t* __restrict__ CeffT) {
    int t = blockIdx.x * 256 + threadIdx.x;
    if (t < 128 * 1024) {
        int n = t >> 10, k = t & 1023;
        int p = n >> 1;
        float sr = params[128 + p], si = params[192 + p];
        float br = Br[p * 1024 + k], bi = Bi[p * 1024 + k];
        float v = (n & 1) ? (sr * bi + si * br) : (sr * br - si * bi);
        W1T[t] = f2bf(v);
    } else {
        int t2 = t - 128 * 1024;
        int h = t2 >> 7, k = t2 & 127;
        int p = k >> 1;
        float v = (k & 1) ? -2.f * Ci[h * 64 + p] : 2.f * Cr[h * 64 + p];
        CeffT[t2] = f2bf(v);
    }
}

// -------------------------------------------- GEMM 1 + fused local scan ----
// Bu[128rows][128cols] computed into registers (cols interleaved re/im),
// dumped to LDS, hierarchically scanned in-LDS (wave-local 32-row scans +
// cross-wave carry combine + correction), then written coalesced to hloc.
// Chunk == block == 128 consecutive l of one batch. Emits chunk end state.
__global__ __launch_bounds__(256) void gemm1s(const float* __restrict__ u,
                                              const ushort_t* __restrict__ W1T,
                                              const float* __restrict__ params,
                                              const float* __restrict__ dApow,
                                              float* __restrict__ hloc,
                                              float* __restrict__ endbuf) {
    __shared__ float bus[128 * 128];            // 64 KB; aliases staging below
    ushort_t* As = (ushort_t*)bus;              // [128][40] bf16
    ushort_t* Bs = As + 128 * 40;               // [128][40] bf16 (20.5 KB used)
    int tid = threadIdx.x;
    int wave = tid >> 6, lane = tid & 63;
    int q = lane >> 4, mn = lane & 15;
    size_t row0 = (size_t)blockIdx.x * 128;
    int r = tid >> 1, half = tid & 1;

    floatx4 acc[2][8] = {};

    for (int kk = 0; kk < 1024; kk += 32) {
        __syncthreads();
        {
            const float4* up = (const float4*)(u + (row0 + r) * 1024 + kk + half * 16);
            float4 f0 = up[0], f1 = up[1], f2 = up[2], f3 = up[3];
            ushort8 t0, t1;
            t0[0] = f2bf(f0.x); t0[1] = f2bf(f0.y); t0[2] = f2bf(f0.z); t0[3] = f2bf(f0.w);
            t0[4] = f2bf(f1.x); t0[5] = f2bf(f1.y); t0[6] = f2bf(f1.z); t0[7] = f2bf(f1.w);
            t1[0] = f2bf(f2.x); t1[1] = f2bf(f2.y); t1[2] = f2bf(f2.z); t1[3] = f2bf(f2.w);
            t1[4] = f2bf(f3.x); t1[5] = f2bf(f3.y); t1[6] = f2bf(f3.z); t1[7] = f2bf(f3.w);
            ushort8* dst = (ushort8*)&As[r * 40 + half * 16];
            dst[0] = t0; dst[1] = t1;
            const ushort8* wp = (const ushort8*)(W1T + r * 1024 + kk + half * 16);
            ushort8* db = (ushort8*)&Bs[r * 40 + half * 16];
            db[0] = wp[0]; db[1] = wp[1];
        }
        __syncthreads();
        s8v a0 = *(const s8v*)&As[(wave * 32 + mn) * 40 + q * 8];
        s8v a1 = *(const s8v*)&As[(wave * 32 + 16 + mn) * 40 + q * 8];
        #pragma unroll
        for (int j = 0; j < 8; j++) {
            s8v bf = *(const s8v*)&Bs[(j * 16 + mn) * 40 + q * 8];
            acc[0][j] = MFMA16(a0, bf, acc[0][j]);
            acc[1][j] = MFMA16(a1, bf, acc[1][j]);
        }
    }
    __syncthreads();   // staging LDS dead; safe to overwrite with Bu tile
    #pragma unroll
    for (int i = 0; i < 2; i++)
        #pragma unroll
        for (int j = 0; j < 8; j++)
            #pragma unroll
            for (int reg = 0; reg < 4; reg++) {
                int row = wave * 32 + i * 16 + q * 4 + reg;
                bus[row * 128 + j * 16 + mn] = acc[i][j][reg];
            }
    __syncthreads();

    // --- wave-local scan over this wave's 32 rows (zero initial state) ---
    float dAr = params[lane], dAi = params[64 + lane];
    float hr = 0.f, hi = 0.f;
    int base = wave * 32 * 128 + 2 * lane;
    #pragma unroll 4
    for (int t = 0; t < 32; t++) {
        float2 v = *(float2*)&bus[base + t * 128];
        float nhr = fmaf(dAr, hr, fmaf(-dAi, hi, v.x));
        float nhi = fmaf(dAr, hi, fmaf(dAi, hr, v.y));
        hr = nhr; hi = nhi;
        *(float2*)&bus[base + t * 128] = make_float2(hr, hi);
    }
    __syncthreads();

    // --- cross-wave carry: c_w = sum_{w'<w} dA^(32*(w-1-w')) * e_{w'} ---
    float a32r = dApow[32 * 128 + 2 * lane], a32i = dApow[32 * 128 + 2 * lane + 1];
    float cr = 0.f, ci = 0.f;
    for (int w2 = 0; w2 < wave; w2++) {
        float2 e = *(float2*)&bus[(w2 * 32 + 31) * 128 + 2 * lane];
        float tr = fmaf(a32r, cr, fmaf(-a32i, ci, e.x));
        float ti = fmaf(a32r, ci, fmaf(a32i, cr, e.y));
        cr = tr; ci = ti;
    }

    // --- correction + coalesced global write: h[l] = h_w[t] + dA^(t+1)*c_w ---
    float* gbase = hloc + (row0 + wave * 32) * 128 + 2 * lane;
    float lr = 0.f, li = 0.f;
    #pragma unroll 4
    for (int t = 0; t < 32; t++) {
        float2 v = *(float2*)&bus[base + t * 128];
        float pr = dApow[(t + 1) * 128 + 2 * lane];
        float pi = dApow[(t + 1) * 128 + 2 * lane + 1];
        float orr = v.x + pr * cr - pi * ci;
        float oi  = v.y + pr * ci + pi * cr;
        *(float2*)(gbase + (size_t)t * 128) = make_float2(orr, oi);
        lr = orr; li = oi;
    }
    if (wave == 3) {   // chunk end state (corrected h at local row 127)
        float* e = endbuf + (size_t)blockIdx.x * 128 + 2 * lane;
        e[0] = lr; e[1] = li;
    }
}

// --------------------------------------------------------- carry scan ----
// carry[c] = state entering chunk c; carry[0] = h0 (folds initial state).
__global__ void scan_carry(const float* __restrict__ endbuf,
                           const float* __restrict__ dApow,
                           const float* __restrict__ h0r,
                           const float* __restrict__ h0i,
                           float* __restrict__ carry) {
    int t = blockIdx.x * 64 + threadIdx.x;  // 512 = 8*64
    int b = t >> 6, p = t & 63;
    float aSr = dApow[S_CH * 128 + 2 * p], aSi = dApow[S_CH * 128 + 2 * p + 1];
    float cr = h0r[b * 64 + p], ci = h0i[b * 64 + p];
    for (int c = 0; c < NC; c++) {
        float* dst = carry + ((size_t)b * NC + c) * 128 + 2 * p;
        dst[0] = cr; dst[1] = ci;
        const float* e = endbuf + ((size_t)b * NC + c) * 128 + 2 * p;
        float er = e[0], ei = e[1];
        float nr = fmaf(aSr, cr, fmaf(-aSi, ci, er));
        float ni = fmaf(aSr, ci, fmaf(aSi, cr, ei));
        cr = nr; ci = ni;
    }
}

// ------------------------------------------------------------- GEMM 2 ----
// Fused fixup + GEMM: A-staging reads h_loc (f32), applies carry correction
// hfix = h_loc + dA^((l mod S)+1) * carry[chunk], converts to bf16 into LDS.
// Also emits h_last (f32, corrected) for rows with l == L-1.
// y[row][h] = sum_k hfix[row][k] * CeffT[h][k] + D[h]*u[row][h]
__global__ __launch_bounds__(256) void gemm2(const float* __restrict__ hloc,
                                             const ushort_t* __restrict__ CeffT,
                                             const float* __restrict__ u,
                                             const float* __restrict__ D,
                                             const float* __restrict__ dApow,
                                             const float* __restrict__ carry,
                                             float* __restrict__ y,
                                             float* __restrict__ out_hlast) {
    __shared__ ushort_t As[128][136];  // [row][k] K=128, stride 272B
    __shared__ ushort_t Bs[128][136];  // [n][k]
    int tid = threadIdx.x;
    int wave = tid >> 6, lane = tid & 63;
    int q = lane >> 4, mn = lane & 15;
    size_t row0 = (size_t)blockIdx.x * 128;
    int r = tid >> 1, half = tid & 1;
    {
        size_t rrow = row0 + r;
        int b = (int)(rrow >> 13);
        int l = (int)(rrow & (L - 1));
        int c = l >> 7;                 // l / S_CH
        int kp = (l & (S_CH - 1)) + 1;
        const float4* hp = (const float4*)(hloc + rrow * 128 + half * 64);
        const float4* pw = (const float4*)(dApow + (size_t)kp * 128 + half * 64);
        const float4* cv = (const float4*)(carry + ((size_t)b * NC + c) * 128 + half * 64);
        ushort8* dst = (ushort8*)&As[r][half * 64];
        bool last = (l == L - 1);
        #pragma unroll
        for (int j = 0; j < 8; j++) {
            float4 hv0 = hp[2 * j], hv1 = hp[2 * j + 1];
            float4 p0 = pw[2 * j], p1 = pw[2 * j + 1];
            float4 c0 = cv[2 * j], c1 = cv[2 * j + 1];
            float r0 = hv0.x + p0.x * c0.x - p0.y * c0.y;
            float i0 = hv0.y + p0.x * c0.y + p0.y * c0.x;
            float r1 = hv0.z + p0.z * c0.z - p0.w * c0.w;
            float i1 = hv0.w + p0.z * c0.w + p0.w * c0.z;
            float r2 = hv1.x + p1.x * c1.x - p1.y * c1.y;
            float i2 = hv1.y + p1.x * c1.y + p1.y * c1.x;
            float r3 = hv1.z + p1.z * c1.z - p1.w * c1.w;
            float i3 = hv1.w + p1.z * c1.w + p1.w * c1.z;
            ushort8 o;
            o[0] = f2bf(r0); o[1] = f2bf(i0); o[2] = f2bf(r1); o[3] = f2bf(i1);
            o[4] = f2bf(r2); o[5] = f2bf(i2); o[6] = f2bf(r3); o[7] = f2bf(i3);
            dst[j] = o;
            if (last) {
                int pb = (half * 64 + j * 8) >> 1;
                out_hlast[b * 64 + pb]           = r0; out_hlast[512 + b * 64 + pb]     = i0;
                out_hlast[b * 64 + pb + 1]       = r1; out_hlast[512 + b * 64 + pb + 1] = i1;
                out_hlast[b * 64 + pb + 2]       = r2; out_hlast[512 + b * 64 + pb + 2] = i2;
                out_hlast[b * 64 + pb + 3]       = r3; out_hlast[512 + b * 64 + pb + 3] = i3;
            }
        }
    }
    for (int ct = 0; ct < 8; ct++) {
        __syncthreads();
        {
            const ushort8* src = (const ushort8*)(CeffT + (size_t)(ct * 128 + r) * 128 + half * 64);
            ushort8* dst = (ushort8*)&Bs[r][half * 64];
            #pragma unroll
            for (int i = 0; i < 8; i++) dst[i] = src[i];
        }
        __syncthreads();
        floatx4 acc[2][8] = {};
        #pragma unroll
        for (int kk = 0; kk < 128; kk += 32) {
            s8v a0 = *(const s8v*)&As[wave * 32 + mn][kk + q * 8];
            s8v a1 = *(const s8v*)&As[wave * 32 + 16 + mn][kk + q * 8];
            #pragma unroll
            for (int j = 0; j < 8; j++) {
                s8v bf = *(const s8v*)&Bs[j * 16 + mn][kk + q * 8];
                acc[0][j] = MFMA16(a0, bf, acc[0][j]);
                acc[1][j] = MFMA16(a1, bf, acc[1][j]);
            }
        }
        float dv[8];
        #pragma unroll
        for (int j = 0; j < 8; j++) dv[j] = D[ct * 128 + j * 16 + mn];
        #pragma unroll
        for (int i = 0; i < 2; i++)
            #pragma unroll
            for (int j = 0; j < 8; j++) {
                int col = ct * 128 + j * 16 + mn;
                #pragma unroll
                for (int reg = 0; reg < 4; reg++) {
                    size_t row = row0 + wave * 32 + i * 16 + q * 4 + reg;
                    y[row * 1024 + col] = acc[i][j][reg] + dv[j] * u[row * 1024 + col];
                }
            }
    }
}

// -------------------------------------------------------------- launch ----
extern "C" void kernel_launch(void* const* d_in, const int* in_sizes, int n_in,
                              void* d_out, int out_size, void* d_ws, size_t ws_size,
                              hipStream_t stream) {
    const float* u      = (const float*)d_in[0];
    const float* h_r    = (const float*)d_in[1];
    const float* h_i    = (const float*)d_in[2];
    const float* A_real = (const float*)d_in[3];
    const float* A_imag = (const float*)d_in[4];
    const float* B_real = (const float*)d_in[5];
    const float* B_imag = (const float*)d_in[6];
    const float* C_real = (const float*)d_in[7];
    const float* C_imag = (const float*)d_in[8];
    const float* D      = (const float*)d_in[9];
    const float* inv_dt = (const float*)d_in[10];
    float* out = (float*)d_out;

    // workspace layout (floats from base; all 16B aligned)
    float* wsf       = (float*)d_ws;
    float* P_params  = wsf;                    // 256 used, reserve 1024
    float* P_dApow   = wsf + 1024;             // 129*128 = 16512, reserve 16640
    float* P_carry   = wsf + 1024 + 16640;     // 8*NC*128 = 65536
    float* P_end     = P_carry + 65536;        // 65536
    ushort_t* P_W1T  = (ushort_t*)(P_end + 65536);      // 128*1024 bf16
    ushort_t* P_Ceff = P_W1T + 128 * 1024;              // 1024*128 bf16
    float* P_Bu      = (float*)(P_Ceff + 1024 * 128);   // 65536*128 f32 (33.5MB)

    params_kernel<<<1, 64, 0, stream>>>(A_real, A_imag, inv_dt, P_params, P_dApow);
    build_w<<<1024, 256, 0, stream>>>(B_real, B_imag, C_real, C_imag, P_params, P_W1T, P_Ceff);
    gemm1s<<<M_TOT / 128, 256, 0, stream>>>(u, P_W1T, P_params, P_dApow, P_Bu, P_end);
    scan_carry<<<8, 64, 0, stream>>>(P_end, P_dApow, h_r, h_i, P_carry);
    gemm2<<<M_TOT / 128, 256, 0, stream>>>(P_Bu, P_Ceff, u, D, P_dApow, P_carry,
                                           out, out + (size_t)M_TOT * H);
}